// Round 12
// baseline (447.242 us; speedup 1.0000x reference)
//
#include <hip/hip_runtime.h>
#include <math.h>

// GENELink forward. adj is 1% sparse, values==1.0 -> ELL sparse ops (~61 nbrs).
// Dense GEMMs: MFMA 16x16x32 bf16 hi/lo split (bf16x3 ~ fp32 accuracy).
// R12: latency attack — build_ell hoists all 6 loads before ballots;
// gather loops broadcast (j, att, dj) via __shfl from softmax registers
// instead of LDS round-trips. Layouts/GEMMs unchanged. 10 dispatches.

#define NN 6144
#define CAP 256

typedef __attribute__((ext_vector_type(8))) short bf16x8;
typedef __attribute__((ext_vector_type(8))) unsigned short u16x8;
typedef __attribute__((ext_vector_type(4))) float f32x4;

__device__ __forceinline__ unsigned short f2bf(float v) {
  unsigned u = __float_as_uint(v);
  unsigned r = u + 0x7fffu + ((u >> 16) & 1u);   // RNE
  return (unsigned short)(r >> 16);
}
__device__ __forceinline__ float bf2f(unsigned short h) {
  return __uint_as_float(((unsigned)h) << 16);
}
__device__ __forceinline__ float wave_max(float v) {
#pragma unroll
  for (int off = 32; off > 0; off >>= 1) v = fmaxf(v, __shfl_xor(v, off));
  return v;
}
__device__ __forceinline__ float wave_sum(float v) {
#pragma unroll
  for (int off = 32; off > 0; off >>= 1) v += __shfl_xor(v, off);
  return v;
}
__device__ __forceinline__ float selu_f(float x) {
  const float sc = 1.0507009873554805f, al = 1.6732632423543772f;
  return x > 0.0f ? sc * x : sc * al * (__expf(x) - 1.0f);
}
__device__ __forceinline__ float leaky2(float x) { return x > 0.f ? x : 0.2f * x; }
// write 4 consecutive cols (k0 % 4 == 0) of row m into A-pack layout (KC=K/32)
__device__ __forceinline__ void write_apack4(unsigned short* __restrict__ Ah,
    unsigned short* __restrict__ Al, int KC, int m, int k0,
    float v0, float v1, float v2, float v3) {
  int mt = m >> 4, c = k0 >> 5;
  int lane = ((k0 >> 3) & 3) * 16 + (m & 15);
  int j = k0 & 7;
  size_t base = ((size_t)(mt * KC + c) * 64 + lane) * 8 + j;
  ushort4 hi, lo;
  hi.x = f2bf(v0); lo.x = f2bf(v0 - bf2f(hi.x));
  hi.y = f2bf(v1); lo.y = f2bf(v1 - bf2f(hi.y));
  hi.z = f2bf(v2); lo.z = f2bf(v2 - bf2f(hi.z));
  hi.w = f2bf(v3); lo.w = f2bf(v3 - bf2f(hi.w));
  *(ushort4*)(Ah + base) = hi;
  *(ushort4*)(Al + base) = lo;
}

// ---------------- adjacency -> ELL, 2-pass, 4 waves/row ----------------------
// R12: all 6 float4 loads hoisted ahead of the ballot chain (6 in flight).
__global__ __launch_bounds__(256) void build_ell(const float* __restrict__ adj,
    unsigned short* __restrict__ nbr, int* __restrict__ deg,
    int* __restrict__ selfflag, float* __restrict__ dis)
{
  __shared__ unsigned long long mS[4][6][4];
  __shared__ int cntS[4];
  __shared__ int selfS;
  int i = blockIdx.x;
  int t = threadIdx.x, lane = t & 63, w = t >> 6;
  if (t == 0) selfS = 0;
  const float* row = adj + (size_t)i * NN + w * 1536;
  float4 v[6];
#pragma unroll
  for (int it = 0; it < 6; ++it)
    v[it] = *(const float4*)(row + it * 256 + lane * 4);
  int cnt = 0;
  int hasself = 0;
#pragma unroll
  for (int it = 0; it < 6; ++it) {
    unsigned long long m0 = __ballot(v[it].x != 0.0f);
    unsigned long long m1 = __ballot(v[it].y != 0.0f);
    unsigned long long m2 = __ballot(v[it].z != 0.0f);
    unsigned long long m3 = __ballot(v[it].w != 0.0f);
    if (lane == 0) {
      mS[w][it][0] = m0; mS[w][it][1] = m1; mS[w][it][2] = m2; mS[w][it][3] = m3;
    }
    cnt += __popcll(m0) + __popcll(m1) + __popcll(m2) + __popcll(m3);
  }
  if (lane == 0) cntS[w] = cnt;
  __syncthreads();
  int base = 0;
  for (int ww = 0; ww < w; ++ww) base += cntS[ww];
  unsigned long long below = (1ull << lane) - 1ull;
#pragma unroll
  for (int it = 0; it < 6; ++it) {
    unsigned long long m0 = mS[w][it][0], m1 = mS[w][it][1];
    unsigned long long m2 = mS[w][it][2], m3 = mS[w][it][3];
    int pre = __popcll(m0 & below) + __popcll(m1 & below) +
              __popcll(m2 & below) + __popcll(m3 & below);
    int c = w * 1536 + it * 256 + lane * 4;
    int p = base + pre;
    if ((m0 >> lane) & 1) { if (p < CAP) nbr[(size_t)i * CAP + p] = (unsigned short)c;     if (c == i) hasself = 1; p++; }
    if ((m1 >> lane) & 1) { if (p < CAP) nbr[(size_t)i * CAP + p] = (unsigned short)(c+1); if (c+1 == i) hasself = 1; p++; }
    if ((m2 >> lane) & 1) { if (p < CAP) nbr[(size_t)i * CAP + p] = (unsigned short)(c+2); if (c+2 == i) hasself = 1; p++; }
    if ((m3 >> lane) & 1) { if (p < CAP) nbr[(size_t)i * CAP + p] = (unsigned short)(c+3); if (c+3 == i) hasself = 1; }
    base += __popcll(m0) + __popcll(m1) + __popcll(m2) + __popcll(m3);
  }
  if (hasself) selfS = 1;
  __syncthreads();
  if (t == 0) {
    int total = cntS[0] + cntS[1] + cntS[2] + cntS[3];
    deg[i] = total < CAP ? total : CAP;
    selfflag[i] = selfS;
    dis[i] = (total > 0) ? rsqrtf((float)total) : 0.0f;  // rowsum == degree
  }
}

// ---------------- mega pack: all weights + x A-pack + fg-buffer zero ---------
__global__ __launch_bounds__(256) void pack_all(const float* __restrict__ gcn_W,
    const float* __restrict__ hgat_W, const float* __restrict__ l1_W,
    const float* __restrict__ l2_W, const float* __restrict__ l2_rW,
    const float* __restrict__ x,
    unsigned short* __restrict__ Bh, unsigned short* __restrict__ Bl,
    unsigned short* __restrict__ Ah, unsigned short* __restrict__ Al,
    float* __restrict__ fgZ)
{
  int idx = blockIdx.x * 256 + threadIdx.x;
  if (idx >= 520192) return;
  if (idx >= 458752) { fgZ[idx - 458752] = 0.0f; return; }
  if (idx >= 65536) {
    int rel = idx - 65536;
    int l = rel & 63;
    int mc = rel >> 6;
    int c = mc & 15, mt = mc >> 4;
    int m = mt * 16 + (l & 15);
    int kb = c * 32 + (l >> 4) * 8;
    const float* src = x + (size_t)m * 512 + kb;
    bf16x8 vh, vl;
#pragma unroll
    for (int j = 0; j < 8; ++j) {
      float v = src[j];
      unsigned short h = f2bf(v);
      vh[j] = (short)h;
      vl[j] = (short)f2bf(v - bf2f(h));
    }
    *(bf16x8*)(Ah + (size_t)rel * 8) = vh;
    *(bf16x8*)(Al + (size_t)rel * 8) = vl;
    return;
  }
  const float* B; int K, N, rel;
  if (idx < 32768) {
    B = (idx < 16384) ? gcn_W : hgat_W; K = 512; N = 256; rel = idx & 16383;
  } else if (idx < 49152) {
    B = (idx < 40960) ? l1_W : (l1_W + 65536); K = 256; N = 256; rel = (idx - 32768) & 8191;
  } else {
    int s = (idx - 49152) >> 12;
    B = (s == 0) ? l2_W : (s == 1) ? (l2_W + 32768) : (s == 2) ? l2_rW : (l2_rW + 32768);
    K = 256; N = 128; rel = (idx - 49152) & 4095;
  }
  int l = rel & 63;
  int tc = rel >> 6;
  int KC = K >> 5;
  int c = tc % KC, t = tc / KC;
  int n = t * 16 + (l & 15);
  int kb = c * 32 + (l >> 4) * 8;
  bf16x8 vh, vl;
#pragma unroll
  for (int j = 0; j < 8; ++j) {
    float v = B[(size_t)(kb + j) * N + n];
    unsigned short h = f2bf(v);
    vh[j] = (short)h;
    vl[j] = (short)f2bf(v - bf2f(h));
  }
  *(bf16x8*)(Bh + (size_t)idx * 8) = vh;
  *(bf16x8*)(Bl + (size_t)idx * 8) = vl;
}

// ---------------- MFMA GEMM, nt=2, z-heads; interleaved/bf16/fp32 writes;
//                  fused f/g epilogue (flat or interleaved) -------------------
__global__ __launch_bounds__(256) void gemm_mfma(
    const unsigned short* __restrict__ Ah, const unsigned short* __restrict__ Al,
    const unsigned short* __restrict__ Bh, const unsigned short* __restrict__ Bl,
    void* C0, void* C1, void* C2, void* C3,
    const float* b0, const float* b1, const float* b2, const float* b3,
    int KC, int N, long bStride8, int obf16mask, int ileaveG,
    int fgmask, int fgIleave, const float* __restrict__ aBase,
    float* __restrict__ fBase, float* __restrict__ gBase)
{
  int z = blockIdx.z;
  void* C = (z == 0) ? C0 : (z == 1) ? C1 : (z == 2) ? C2 : C3;
  const float* bias = (z == 0) ? b0 : (z == 1) ? b1 : (z == 2) ? b2 : b3;
  int obf = (obf16mask >> z) & 1;
  int ilv = (ileaveG && z < 2) ? ileaveG : 0;
  int wave = threadIdx.x >> 6, lane = threadIdx.x & 63;
  int mt = blockIdx.x * 4 + wave;
  int tg0 = blockIdx.y * 2;
  f32x4 acc[2];
  acc[0] = (f32x4){0.f, 0.f, 0.f, 0.f};
  acc[1] = (f32x4){0.f, 0.f, 0.f, 0.f};
  const bf16x8* ah = (const bf16x8*)Ah + (size_t)mt * KC * 64 + lane;
  const bf16x8* al = (const bf16x8*)Al + (size_t)mt * KC * 64 + lane;
  const bf16x8* bh = (const bf16x8*)Bh + (size_t)z * bStride8 + lane;
  const bf16x8* bl = (const bf16x8*)Bl + (size_t)z * bStride8 + lane;
  for (int c = 0; c < KC; ++c) {
    bf16x8 a_h = ah[c * 64];
    bf16x8 a_l = al[c * 64];
#pragma unroll
    for (int t = 0; t < 2; ++t) {
      size_t bo = (size_t)((tg0 + t) * KC + c) * 64;
      bf16x8 b_h = bh[bo];
      bf16x8 b_l = bl[bo];
      acc[t] = __builtin_amdgcn_mfma_f32_16x16x32_bf16(a_h, b_h, acc[t], 0, 0, 0);
      acc[t] = __builtin_amdgcn_mfma_f32_16x16x32_bf16(a_h, b_l, acc[t], 0, 0, 0);
      acc[t] = __builtin_amdgcn_mfma_f32_16x16x32_bf16(a_l, b_h, acc[t], 0, 0, 0);
    }
  }
  int quad = lane >> 4, cn = lane & 15;
#pragma unroll
  for (int t = 0; t < 2; ++t) {
    int col = (tg0 + t) * 16 + cn;
    float bv = bias ? bias[col] : 0.0f;
#pragma unroll
    for (int r = 0; r < 4; ++r) {
      int row = mt * 16 + quad * 4 + r;
      float v = acc[t][r] + bv;
      acc[t][r] = v;
      if (ilv) {
        size_t addr = (size_t)row * (2 * N) + (size_t)(col / ilv) * (2 * ilv)
                    + z * ilv + (col % ilv);
        ((unsigned short*)C0)[addr] = f2bf(v);
      } else if (obf) {
        ((unsigned short*)C)[(size_t)row * N + col] = f2bf(v);
      } else {
        ((float*)C)[(size_t)row * N + col] = v;
      }
    }
  }
  if ((fgmask >> z) & 1) {
    const float* af = aBase + (size_t)z * 2 * N;
    const float* ag = af + N;
    float af0 = af[tg0 * 16 + cn], af1 = af[(tg0 + 1) * 16 + cn];
    float ag0 = ag[tg0 * 16 + cn], ag1 = ag[(tg0 + 1) * 16 + cn];
#pragma unroll
    for (int r = 0; r < 4; ++r) {
      float pf = acc[0][r] * af0 + acc[1][r] * af1;
      float pg = acc[0][r] * ag0 + acc[1][r] * ag1;
#pragma unroll
      for (int off = 1; off < 16; off <<= 1) {
        pf += __shfl_xor(pf, off);
        pg += __shfl_xor(pg, off);
      }
      if (cn == 0) {
        int row = mt * 16 + quad * 4 + r;
        size_t fo = fgIleave ? ((size_t)row * 2 + z) : ((size_t)z * NN + row);
        atomicAdd(fBase + fo, pf);
        atomicAdd(gBase + fo, pg);
      }
    }
  }
}

// ---------------- conv GAT: wave-per-row, BOTH heads, shfl-broadcast edges ---
// fI/gI interleaved [NN][2]; hh interleaved [row][grp][head][G].
// MODE 1 (D=256,G=4): apack(selu(0.5*(o0+o1) + res)); MODE 2 (D=128,G=2): emb.
template<int D, int MODE>
__global__ __launch_bounds__(256) void gat_wave(const unsigned short* __restrict__ nbr,
    const int* __restrict__ deg, const int* __restrict__ selfflag,
    const float* __restrict__ fI, const float* __restrict__ gI,
    const unsigned short* __restrict__ hh, const float* __restrict__ bias,
    const float* __restrict__ res,
    unsigned short* __restrict__ Ah, unsigned short* __restrict__ Al,
    float* __restrict__ emb)
{
  int t = threadIdx.x, lane = t & 63, w = t >> 6;
  int row = blockIdx.x * 4 + w;
  int dg = deg[row];
  int klen = dg + (selfflag[row] ? 0 : 1);   // gat_adj = adj + I
  if (klen > 128) klen = 128;
  float f0 = fI[2 * row], f1 = fI[2 * row + 1];
  // dual softmax over shared edge list; per-lane regs hold edges lane, lane+64
  float e00 = -3.0e38f, e01 = -3.0e38f, e10 = -3.0e38f, e11 = -3.0e38f;
  int j0 = 0, j1 = 0;
  if (lane < klen) {
    j0 = (lane < dg) ? (int)nbr[(size_t)row * CAP + lane] : row;
    float2 gj = *(const float2*)(gI + 2 * j0);
    e00 = leaky2(f0 + gj.x);
    e01 = leaky2(f1 + gj.y);
  }
  if (lane + 64 < klen) {
    j1 = (lane + 64 < dg) ? (int)nbr[(size_t)row * CAP + lane + 64] : row;
    float2 gj = *(const float2*)(gI + 2 * j1);
    e10 = leaky2(f0 + gj.x);
    e11 = leaky2(f1 + gj.y);
  }
  float m0 = wave_max(fmaxf(e00, e10));
  float m1 = wave_max(fmaxf(e01, e11));
  float a00 = (lane < klen) ? __expf(e00 - m0) : 0.0f;       // head0 edge lane
  float a10 = (lane + 64 < klen) ? __expf(e10 - m0) : 0.0f;  // head0 edge lane+64
  float a01 = (lane < klen) ? __expf(e01 - m1) : 0.0f;       // head1 edge lane
  float a11 = (lane + 64 < klen) ? __expf(e11 - m1) : 0.0f;  // head1 edge lane+64
  float inv0 = 1.0f / wave_sum(a00 + a10);
  float inv1 = 1.0f / wave_sum(a01 + a11);
  a00 *= inv0; a10 *= inv0;
  a01 *= inv1; a11 *= inv1;

  if (MODE == 1) {
    // lane owns cols 4l..4l+3 for both heads; one 16B load per edge
    const unsigned short* hp = hh + 8 * lane;
    float4 o0 = {0.f, 0.f, 0.f, 0.f}, o1 = {0.f, 0.f, 0.f, 0.f};
#pragma unroll 4
    for (int k = 0; k < klen; ++k) {
      int sel = k & 64, src = k & 63;
      int jj = __shfl(sel ? j1 : j0, src);
      float ah0 = __shfl(sel ? a10 : a00, src);
      float ah1 = __shfl(sel ? a11 : a01, src);
      u16x8 hv = *(const u16x8*)(hp + (size_t)jj * 512);
      o0.x += ah0 * bf2f(hv[0]); o1.x += ah1 * bf2f(hv[4]);
      o0.y += ah0 * bf2f(hv[1]); o1.y += ah1 * bf2f(hv[5]);
      o0.z += ah0 * bf2f(hv[2]); o1.z += ah1 * bf2f(hv[6]);
      o0.w += ah0 * bf2f(hv[3]); o1.w += ah1 * bf2f(hv[7]);
    }
    o0.x = leaky2(o0.x); o0.y = leaky2(o0.y); o0.z = leaky2(o0.z); o0.w = leaky2(o0.w);
    o1.x = leaky2(o1.x); o1.y = leaky2(o1.y); o1.z = leaky2(o1.z); o1.w = leaky2(o1.w);
    float q0 = wave_sum(o0.x * o0.x + o0.y * o0.y + o0.z * o0.z + o0.w * o0.w);
    float q1 = wave_sum(o1.x * o1.x + o1.y * o1.y + o1.z * o1.z + o1.w * o1.w);
    float n0 = 1.0f / fmaxf(sqrtf(q0), 1e-12f);
    float n1 = 1.0f / fmaxf(sqrtf(q1), 1e-12f);
    int c = 4 * lane;
    float4 b0v = *(const float4*)(bias + c);
    float4 b1v = *(const float4*)(bias + D + c);
    float4 hv = *(const float4*)(res + (size_t)row * D + c);
    float v0 = selu_f(0.5f * ((o0.x * n0 + b0v.x) + (o1.x * n1 + b1v.x)) + hv.x);
    float v1 = selu_f(0.5f * ((o0.y * n0 + b0v.y) + (o1.y * n1 + b1v.y)) + hv.y);
    float v2 = selu_f(0.5f * ((o0.z * n0 + b0v.z) + (o1.z * n1 + b1v.z)) + hv.z);
    float v3 = selu_f(0.5f * ((o0.w * n0 + b0v.w) + (o1.w * n1 + b1v.w)) + hv.w);
    write_apack4(Ah, Al, 8, row, c, v0, v1, v2, v3);
  } else {
    // D=128: lane owns cols 2l,2l+1 for both heads; one 8B load per edge
    const unsigned short* hp = hh + 4 * lane;
    float o0x = 0.f, o0y = 0.f, o1x = 0.f, o1y = 0.f;
#pragma unroll 4
    for (int k = 0; k < klen; ++k) {
      int sel = k & 64, src = k & 63;
      int jj = __shfl(sel ? j1 : j0, src);
      float ah0 = __shfl(sel ? a10 : a00, src);
      float ah1 = __shfl(sel ? a11 : a01, src);
      ushort4 hv = *(const ushort4*)(hp + (size_t)jj * 256);
      o0x += ah0 * bf2f(hv.x); o0y += ah0 * bf2f(hv.y);
      o1x += ah1 * bf2f(hv.z); o1y += ah1 * bf2f(hv.w);
    }
    o0x = leaky2(o0x); o0y = leaky2(o0y);
    o1x = leaky2(o1x); o1y = leaky2(o1y);
    float q0 = wave_sum(o0x * o0x + o0y * o0y);
    float q1 = wave_sum(o1x * o1x + o1y * o1y);
    float n0 = 1.0f / fmaxf(sqrtf(q0), 1e-12f);
    float n1 = 1.0f / fmaxf(sqrtf(q1), 1e-12f);
    int c = 2 * lane;
    float2 b0v = *(const float2*)(bias + c);
    float2 b1v = *(const float2*)(bias + D + c);
    float2 r0 = *(const float2*)(res + (size_t)row * D + c);
    float2 r1 = *(const float2*)(res + (size_t)NN * D + (size_t)row * D + c);
    float2 o;
    o.x = 0.5f * (((o0x * n0 + b0v.x) + r0.x) + ((o1x * n1 + b1v.x) + r1.x));
    o.y = 0.5f * (((o0y * n0 + b0v.y) + r0.y) + ((o1y * n1 + b1v.y) + r1.y));
    *(float2*)(emb + (size_t)row * D + c) = o;
  }
}

// ---------------- fused hybrid: wave-per-row; shfl-broadcast edges -----------
__global__ __launch_bounds__(256) void fused_hybrid(const unsigned short* __restrict__ nbr,
    const int* __restrict__ deg, const float* __restrict__ dis,
    const unsigned short* __restrict__ XH,   // interleaved [row][grp][branch][4]
    const float* __restrict__ f, const float* __restrict__ g,
    const float* __restrict__ bias, const float* __restrict__ eta,
    float* __restrict__ hout, unsigned short* __restrict__ Ah,
    unsigned short* __restrict__ Al)
{
  int t = threadIdx.x, lane = t & 63, w = t >> 6;
  int row = blockIdx.x * 4 + w;
  int klen = deg[row];
  if (klen > 128) klen = 128;
  float fi = f[row];
  float e0 = -3.0e38f, e1 = -3.0e38f;
  int j0 = 0, j1 = 0;
  float d0 = 0.f, d1 = 0.f;
  if (lane < klen) {
    j0 = (int)nbr[(size_t)row * CAP + lane];
    d0 = dis[j0];
    float ev = leaky2(fi + g[j0]);
    e0 = (d0 > 0.0f) ? ev : -3.0e38f;
  }
  if (lane + 64 < klen) {
    j1 = (int)nbr[(size_t)row * CAP + lane + 64];
    d1 = dis[j1];
    float ev = leaky2(fi + g[j1]);
    e1 = (d1 > 0.0f) ? ev : -3.0e38f;
  }
  float m = wave_max(fmaxf(e0, e1));
  float a0 = (lane < klen) ? __expf(e0 - m) : 0.0f;
  float a1 = (lane + 64 < klen) ? __expf(e1 - m) : 0.0f;
  float inv = 1.0f / wave_sum(a0 + a1);
  a0 *= inv; a1 *= inv;

  const unsigned short* hp = XH + 8 * lane;   // branch0=xw [0..3], branch1=hh [4..7]
  float4 accG = {0.f, 0.f, 0.f, 0.f};
  float4 accA = {0.f, 0.f, 0.f, 0.f};
#pragma unroll 4
  for (int k = 0; k < klen; ++k) {
    int sel = k & 64, src = k & 63;
    int jj = __shfl(sel ? j1 : j0, src);
    float a = __shfl(sel ? a1 : a0, src);
    float dj = __shfl(sel ? d1 : d0, src);
    u16x8 hv = *(const u16x8*)(hp + (size_t)jj * 512);
    accG.x += dj * bf2f(hv[0]); accA.x += a * bf2f(hv[4]);
    accG.y += dj * bf2f(hv[1]); accA.y += a * bf2f(hv[5]);
    accG.z += dj * bf2f(hv[2]); accA.z += a * bf2f(hv[6]);
    accG.w += dj * bf2f(hv[3]); accA.w += a * bf2f(hv[7]);
  }
  accA.x = leaky2(accA.x); accA.y = leaky2(accA.y);
  accA.z = leaky2(accA.z); accA.w = leaky2(accA.w);
  float q = wave_sum(accA.x * accA.x + accA.y * accA.y +
                     accA.z * accA.z + accA.w * accA.w);
  float nsc = 1.0f / fmaxf(sqrtf(q), 1e-12f);
  float di = dis[row];
  float et = eta[0];
  const float* bp = bias + 4 * lane;
  float ga[4] = {accG.x, accG.y, accG.z, accG.w};
  float at[4] = {accA.x, accA.y, accA.z, accA.w};
  float hv4[4];
#pragma unroll
  for (int u = 0; u < 4; ++u) {
    float gcn = leaky2(di * ga[u]);
    float gat = at[u] * nsc + bp[u];
    float z = et * gcn + (1.0f - et) * gat;
    hv4[u] = selu_f(z);
  }
  *(float4*)(hout + (size_t)row * 256 + 4 * lane) =
      (float4){hv4[0], hv4[1], hv4[2], hv4[3]};
  write_apack4(Ah, Al, 8, row, 4 * lane, hv4[0], hv4[1], hv4[2], hv4[3]);
}

// ---------------- fused decoder MLPs (leaky 0.01), 16 rows/block -------------
__global__ __launch_bounds__(256) void decoder_fused(const float* __restrict__ emb,
    const float* __restrict__ tf1_W, const float* __restrict__ tf1_b,
    const float* __restrict__ tf2_W, const float* __restrict__ tf2_b,
    const float* __restrict__ tg1_W, const float* __restrict__ tg1_b,
    const float* __restrict__ tg2_W, const float* __restrict__ tg2_b,
    float* __restrict__ TF, float* __restrict__ TG)
{
  __shared__ float embS[128 * 16];   // [k][r]
  __shared__ float t1S[128 * 16];    // [c][r]
  int t = threadIdx.x;
  int r0 = blockIdx.x * 16;
  for (int e = t; e < 2048; e += 256) {
    int r = e >> 7, k = e & 127;
    embS[k * 16 + r] = emb[(size_t)(r0 + r) * 128 + k];
  }
  __syncthreads();
  int c = t & 127, half = t >> 7;
  const float* W1 = (c < 64) ? tf1_W : tg1_W;
  int c1 = c & 63;
  float b1v = (c < 64) ? tf1_b[c1] : tg1_b[c1];
  float acc1[8];
#pragma unroll
  for (int r = 0; r < 8; ++r) acc1[r] = b1v;
  for (int k = 0; k < 128; ++k) {
    float wv = W1[k * 64 + c1];
#pragma unroll
    for (int r = 0; r < 8; ++r) acc1[r] += wv * embS[k * 16 + half * 8 + r];
  }
#pragma unroll
  for (int r = 0; r < 8; ++r) {
    float v = acc1[r];
    t1S[c * 16 + half * 8 + r] = v > 0.0f ? v : 0.01f * v;
  }
  __syncthreads();
  int c2 = t & 63, rg = t >> 6;
  const float* W2 = (c2 < 32) ? tf2_W : tg2_W;
  int cc = c2 & 31;
  float b2v = (c2 < 32) ? tf2_b[cc] : tg2_b[cc];
  int koff = (c2 < 32) ? 0 : 64;
  float acc2[4];
#pragma unroll
  for (int r = 0; r < 4; ++r) acc2[r] = b2v;
  for (int k = 0; k < 64; ++k) {
    float wv = W2[k * 32 + cc];
#pragma unroll
    for (int r = 0; r < 4; ++r) acc2[r] += wv * t1S[(koff + k) * 16 + rg * 4 + r];
  }
  float* O = (c2 < 32) ? TF : TG;
#pragma unroll
  for (int r = 0; r < 4; ++r) {
    float v = acc2[r];
    v = v > 0.0f ? v : 0.01f * v;
    O[(size_t)(r0 + rg * 4 + r) * 32 + cc] = v;
  }
}

// ---------------- final gather + MLP -----------------------------------------
__global__ void decode_mlp(const float* __restrict__ tf,
    const float* __restrict__ tg, const int* __restrict__ samp,
    const float* __restrict__ W, const float* __restrict__ b,
    float* __restrict__ out, int B)
{
  int bid = blockIdx.x * blockDim.x + threadIdx.x;
  if (bid >= B) return;
  int s0 = samp[2 * bid], s1 = samp[2 * bid + 1];
  float a0 = b[0], a1 = b[1];
#pragma unroll
  for (int c = 0; c < 32; ++c) {
    float v = tf[(size_t)s0 * 32 + c];
    a0 += v * W[2 * c];
    a1 += v * W[2 * c + 1];
  }
#pragma unroll
  for (int c = 0; c < 32; ++c) {
    float v = tg[(size_t)s1 * 32 + c];
    a0 += v * W[2 * (32 + c)];
    a1 += v * W[2 * (32 + c) + 1];
  }
  out[2 * bid] = a0;
  out[2 * bid + 1] = a1;
}

// ---------------- driver ------------------------------------------------------
extern "C" void kernel_launch(void* const* d_in, const int* in_sizes, int n_in,
                              void* d_out, int out_size, void* d_ws, size_t ws_size,
                              hipStream_t stream)
{
  const float* x      = (const float*)d_in[0];
  const float* adj    = (const float*)d_in[1];
  const float* gcn_W  = (const float*)d_in[2];
  const float* gcn_b  = (const float*)d_in[3];
  const float* hgat_W = (const float*)d_in[4];
  const float* hgat_a = (const float*)d_in[5];
  const float* hgat_b = (const float*)d_in[6];
  const float* eta    = (const float*)d_in[7];
  const float* l1_W   = (const float*)d_in[8];
  const float* l1_a   = (const float*)d_in[9];
  const float* l1_b   = (const float*)d_in[10];
  const float* l2_W   = (const float*)d_in[11];
  const float* l2_a   = (const float*)d_in[12];
  const float* l2_b   = (const float*)d_in[13];
  const float* l2_rW  = (const float*)d_in[14];
  const float* l2_rb  = (const float*)d_in[15];
  const float* tf1_W  = (const float*)d_in[16];
  const float* tf1_b  = (const float*)d_in[17];
  const float* tf2_W  = (const float*)d_in[18];
  const float* tf2_b  = (const float*)d_in[19];
  const float* tg1_W  = (const float*)d_in[20];
  const float* tg1_b  = (const float*)d_in[21];
  const float* tg2_W  = (const float*)d_in[22];
  const float* tg2_b  = (const float*)d_in[23];
  const float* mlp_W  = (const float*)d_in[24];
  const float* mlp_b  = (const float*)d_in[25];
  const int*   samp   = (const int*)d_in[26];
  float* out = (float*)d_out;

  char* ws = (char*)d_ws;
  size_t off = 0;
  auto alloc = [&](size_t bytes) -> void* {
    void* p = ws + off;
    off += (bytes + 255) & ~(size_t)255;
    return p;
  };
  unsigned short* nbr = (unsigned short*)alloc((size_t)NN * CAP * 2);
  int*   deg = (int*)  alloc((size_t)NN * 4);
  int*   sfl = (int*)  alloc((size_t)NN * 4);
  float* dis = (float*)alloc((size_t)NN * 4);
  float* fgZ = (float*)alloc((size_t)10 * NN * 4);
  unsigned short* H0b = (unsigned short*)alloc((size_t)2 * NN * 256 * 2);  // xw|hh interleaved
  float* Hh  = (float*)alloc((size_t)NN * 256 * 4);                        // h (fp32 residual)
  unsigned short* HHb = (unsigned short*)alloc((size_t)2 * NN * 256 * 2);  // conv1 heads interleaved
  unsigned short* Qb  = (unsigned short*)alloc((size_t)2 * NN * 128 * 2);  // conv2 heads interleaved
  float* Qr  = (float*)alloc((size_t)2 * NN * 128 * 4);                    // conv2 residual fp32
  float* emb = (float*)alloc((size_t)NN * 128 * 4);
  float* TF  = (float*)alloc((size_t)NN * 32 * 4);
  float* TG  = (float*)alloc((size_t)NN * 32 * 4);
  unsigned short* APH = (unsigned short*)alloc((size_t)NN * 512 * 2);  // shared A arena
  unsigned short* APL = (unsigned short*)alloc((size_t)NN * 512 * 2);
  unsigned short* BPH = (unsigned short*)alloc((size_t)65536 * 8 * 2);
  unsigned short* BPL = (unsigned short*)alloc((size_t)65536 * 8 * 2);
  (void)ws_size; (void)n_in; (void)in_sizes; (void)out_size;

  float* fv0 = fgZ;                 // [NN] flat   (hybrid, z=1 of gemm1)
  float* gv0 = fgZ + NN;
  float* fI1 = fgZ + 2 * NN;        // [NN][2] interleaved (conv1 heads)
  float* gI1 = fgZ + 4 * NN;
  float* fI2 = fgZ + 6 * NN;        // [NN][2] interleaved (conv2 heads)
  float* gI2 = fgZ + 8 * NN;

  const float* nil = nullptr;

  // 1-2. sparsify adjacency; pack all weights + x + zero fg buffers
  build_ell<<<NN, 256, 0, stream>>>(adj, nbr, deg, sfl, dis);
  pack_all<<<2032, 256, 0, stream>>>(gcn_W, hgat_W, l1_W, l2_W, l2_rW, x,
      BPH, BPL, APH, APL, fgZ);

  // 3-4. hybrid layer (xw/hh interleaved; fg flat on z=1)
  gemm_mfma<<<dim3(96, 8, 2), 256, 0, stream>>>(APH, APL, BPH, BPL,
      H0b, nullptr, nullptr, nullptr, gcn_b, nil, nil, nil,
      16, 256, 16384, 0x0, 4,
      0x2, 0, hgat_a - 512, fv0 - NN, gv0 - NN);
  fused_hybrid<<<NN / 4, 256, 0, stream>>>(nbr, deg, dis, H0b,
      fv0, gv0, hgat_b, eta, Hh, APH, APL);

  // 5-6. ConvLayer1 (heads interleaved; fg interleaved; in-register combine)
  gemm_mfma<<<dim3(96, 8, 2), 256, 0, stream>>>(APH, APL, BPH + (size_t)32768 * 8,
      BPL + (size_t)32768 * 8, HHb, nullptr, nullptr, nullptr,
      nil, nil, nil, nil, 8, 256, 8192, 0x0, 4,
      0x3, 1, l1_a, fI1, gI1);
  gat_wave<256, 1><<<NN / 4, 256, 0, stream>>>(nbr, deg, sfl, fI1, gI1, HHb, l1_b,
      Hh, APH, APL, nullptr);

  // 7-8. ConvLayer2 (heads interleaved z<2; residuals fp32 z>=2; fg interleaved)
  gemm_mfma<<<dim3(96, 4, 4), 256, 0, stream>>>(APH, APL, BPH + (size_t)49152 * 8,
      BPL + (size_t)49152 * 8,
      Qb, nullptr, Qr, Qr + (size_t)NN * 128,
      nil, nil, l2_rb, l2_rb + 128, 8, 128, 4096, 0x0, 2,
      0x3, 1, l2_a, fI2, gI2);
  gat_wave<128, 2><<<NN / 4, 256, 0, stream>>>(nbr, deg, sfl, fI2, gI2, Qb, l2_b,
      Qr, nullptr, nullptr, emb);

  // 9. fused decoder MLPs
  decoder_fused<<<NN / 16, 256, 0, stream>>>(emb, tf1_W, tf1_b, tf2_W, tf2_b,
      tg1_W, tg1_b, tg2_W, tg2_b, TF, TG);

  // 10. pair gather + final MLP
  decode_mlp<<<16, 256, 0, stream>>>(TF, TG, samp, mlp_W, mlp_b, out, 4096);
}

// Round 13
// 409.037 us; speedup vs baseline: 1.0934x; 1.0934x over previous
//
#include <hip/hip_runtime.h>
#include <math.h>

// GENELink forward. adj is 1% sparse, values==1.0 -> ELL sparse ops (~61 nbrs).
// Dense GEMMs: MFMA 16x16x32 bf16 hi/lo split (bf16x3 ~ fp32 accuracy).
// R13: revert R12's shfl-broadcast gathers to R11's LDS form (shfl in the
// address path serialized the gather; regression +28us). Keep build_ell
// 6-load hoist; merge build_ell+pack_all into one prep dispatch. 9 dispatches.

#define NN 6144
#define CAP 256

typedef __attribute__((ext_vector_type(8))) short bf16x8;
typedef __attribute__((ext_vector_type(8))) unsigned short u16x8;
typedef __attribute__((ext_vector_type(4))) float f32x4;

__device__ __forceinline__ unsigned short f2bf(float v) {
  unsigned u = __float_as_uint(v);
  unsigned r = u + 0x7fffu + ((u >> 16) & 1u);   // RNE
  return (unsigned short)(r >> 16);
}
__device__ __forceinline__ float bf2f(unsigned short h) {
  return __uint_as_float(((unsigned)h) << 16);
}
__device__ __forceinline__ float wave_max(float v) {
#pragma unroll
  for (int off = 32; off > 0; off >>= 1) v = fmaxf(v, __shfl_xor(v, off));
  return v;
}
__device__ __forceinline__ float wave_sum(float v) {
#pragma unroll
  for (int off = 32; off > 0; off >>= 1) v += __shfl_xor(v, off);
  return v;
}
__device__ __forceinline__ float selu_f(float x) {
  const float sc = 1.0507009873554805f, al = 1.6732632423543772f;
  return x > 0.0f ? sc * x : sc * al * (__expf(x) - 1.0f);
}
__device__ __forceinline__ float leaky2(float x) { return x > 0.f ? x : 0.2f * x; }
// write 4 consecutive cols (k0 % 4 == 0) of row m into A-pack layout (KC=K/32)
__device__ __forceinline__ void write_apack4(unsigned short* __restrict__ Ah,
    unsigned short* __restrict__ Al, int KC, int m, int k0,
    float v0, float v1, float v2, float v3) {
  int mt = m >> 4, c = k0 >> 5;
  int lane = ((k0 >> 3) & 3) * 16 + (m & 15);
  int j = k0 & 7;
  size_t base = ((size_t)(mt * KC + c) * 64 + lane) * 8 + j;
  ushort4 hi, lo;
  hi.x = f2bf(v0); lo.x = f2bf(v0 - bf2f(hi.x));
  hi.y = f2bf(v1); lo.y = f2bf(v1 - bf2f(hi.y));
  hi.z = f2bf(v2); lo.z = f2bf(v2 - bf2f(hi.z));
  hi.w = f2bf(v3); lo.w = f2bf(v3 - bf2f(hi.w));
  *(ushort4*)(Ah + base) = hi;
  *(ushort4*)(Al + base) = lo;
}

// ---------------- prep: build_ell (blocks [0,NN)) + pack_all (rest) ----------
// build_ell: 2-pass 4-waves/row, all 6 float4 loads hoisted (in flight).
// pack_all: [0,65536) B packs; [65536,458752) x A-pack; [458752,520192) fg zero.
__global__ __launch_bounds__(256) void prep_kernel(const float* __restrict__ adj,
    unsigned short* __restrict__ nbr, int* __restrict__ deg,
    int* __restrict__ selfflag, float* __restrict__ dis,
    const float* __restrict__ gcn_W, const float* __restrict__ hgat_W,
    const float* __restrict__ l1_W, const float* __restrict__ l2_W,
    const float* __restrict__ l2_rW, const float* __restrict__ x,
    unsigned short* __restrict__ Bh, unsigned short* __restrict__ Bl,
    unsigned short* __restrict__ Ah, unsigned short* __restrict__ Al,
    float* __restrict__ fgZ)
{
  if (blockIdx.x < NN) {
    __shared__ unsigned long long mS[4][6][4];
    __shared__ int cntS[4];
    __shared__ int selfS;
    int i = blockIdx.x;
    int t = threadIdx.x, lane = t & 63, w = t >> 6;
    if (t == 0) selfS = 0;
    const float* row = adj + (size_t)i * NN + w * 1536;
    float4 v[6];
#pragma unroll
    for (int it = 0; it < 6; ++it)
      v[it] = *(const float4*)(row + it * 256 + lane * 4);
    int cnt = 0;
    int hasself = 0;
#pragma unroll
    for (int it = 0; it < 6; ++it) {
      unsigned long long m0 = __ballot(v[it].x != 0.0f);
      unsigned long long m1 = __ballot(v[it].y != 0.0f);
      unsigned long long m2 = __ballot(v[it].z != 0.0f);
      unsigned long long m3 = __ballot(v[it].w != 0.0f);
      if (lane == 0) {
        mS[w][it][0] = m0; mS[w][it][1] = m1; mS[w][it][2] = m2; mS[w][it][3] = m3;
      }
      cnt += __popcll(m0) + __popcll(m1) + __popcll(m2) + __popcll(m3);
    }
    if (lane == 0) cntS[w] = cnt;
    __syncthreads();
    int base = 0;
    for (int ww = 0; ww < w; ++ww) base += cntS[ww];
    unsigned long long below = (1ull << lane) - 1ull;
#pragma unroll
    for (int it = 0; it < 6; ++it) {
      unsigned long long m0 = mS[w][it][0], m1 = mS[w][it][1];
      unsigned long long m2 = mS[w][it][2], m3 = mS[w][it][3];
      int pre = __popcll(m0 & below) + __popcll(m1 & below) +
                __popcll(m2 & below) + __popcll(m3 & below);
      int c = w * 1536 + it * 256 + lane * 4;
      int p = base + pre;
      if ((m0 >> lane) & 1) { if (p < CAP) nbr[(size_t)i * CAP + p] = (unsigned short)c;     if (c == i) hasself = 1; p++; }
      if ((m1 >> lane) & 1) { if (p < CAP) nbr[(size_t)i * CAP + p] = (unsigned short)(c+1); if (c+1 == i) hasself = 1; p++; }
      if ((m2 >> lane) & 1) { if (p < CAP) nbr[(size_t)i * CAP + p] = (unsigned short)(c+2); if (c+2 == i) hasself = 1; p++; }
      if ((m3 >> lane) & 1) { if (p < CAP) nbr[(size_t)i * CAP + p] = (unsigned short)(c+3); if (c+3 == i) hasself = 1; }
      base += __popcll(m0) + __popcll(m1) + __popcll(m2) + __popcll(m3);
    }
    if (hasself) selfS = 1;
    __syncthreads();
    if (t == 0) {
      int total = cntS[0] + cntS[1] + cntS[2] + cntS[3];
      deg[i] = total < CAP ? total : CAP;
      selfflag[i] = selfS;
      dis[i] = (total > 0) ? rsqrtf((float)total) : 0.0f;  // rowsum == degree
    }
    return;
  }
  // ---- pack half ----
  int idx = (blockIdx.x - NN) * 256 + threadIdx.x;
  if (idx >= 520192) return;
  if (idx >= 458752) { fgZ[idx - 458752] = 0.0f; return; }
  if (idx >= 65536) {
    int rel = idx - 65536;
    int l = rel & 63;
    int mc = rel >> 6;
    int c = mc & 15, mt = mc >> 4;
    int m = mt * 16 + (l & 15);
    int kb = c * 32 + (l >> 4) * 8;
    const float* src = x + (size_t)m * 512 + kb;
    bf16x8 vh, vl;
#pragma unroll
    for (int j = 0; j < 8; ++j) {
      float v = src[j];
      unsigned short h = f2bf(v);
      vh[j] = (short)h;
      vl[j] = (short)f2bf(v - bf2f(h));
    }
    *(bf16x8*)(Ah + (size_t)rel * 8) = vh;
    *(bf16x8*)(Al + (size_t)rel * 8) = vl;
    return;
  }
  const float* B; int K, N, rel;
  if (idx < 32768) {
    B = (idx < 16384) ? gcn_W : hgat_W; K = 512; N = 256; rel = idx & 16383;
  } else if (idx < 49152) {
    B = (idx < 40960) ? l1_W : (l1_W + 65536); K = 256; N = 256; rel = (idx - 32768) & 8191;
  } else {
    int s = (idx - 49152) >> 12;
    B = (s == 0) ? l2_W : (s == 1) ? (l2_W + 32768) : (s == 2) ? l2_rW : (l2_rW + 32768);
    K = 256; N = 128; rel = (idx - 49152) & 4095;
  }
  int l = rel & 63;
  int tc = rel >> 6;
  int KC = K >> 5;
  int c = tc % KC, t2 = tc / KC;
  int n = t2 * 16 + (l & 15);
  int kb = c * 32 + (l >> 4) * 8;
  bf16x8 vh, vl;
#pragma unroll
  for (int j = 0; j < 8; ++j) {
    float v = B[(size_t)(kb + j) * N + n];
    unsigned short h = f2bf(v);
    vh[j] = (short)h;
    vl[j] = (short)f2bf(v - bf2f(h));
  }
  *(bf16x8*)(Bh + (size_t)idx * 8) = vh;
  *(bf16x8*)(Bl + (size_t)idx * 8) = vl;
}

// ---------------- MFMA GEMM, nt=2, z-heads; interleaved/bf16/fp32 writes;
//                  fused f/g epilogue (flat or interleaved) -------------------
__global__ __launch_bounds__(256) void gemm_mfma(
    const unsigned short* __restrict__ Ah, const unsigned short* __restrict__ Al,
    const unsigned short* __restrict__ Bh, const unsigned short* __restrict__ Bl,
    void* C0, void* C1, void* C2, void* C3,
    const float* b0, const float* b1, const float* b2, const float* b3,
    int KC, int N, long bStride8, int obf16mask, int ileaveG,
    int fgmask, int fgIleave, const float* __restrict__ aBase,
    float* __restrict__ fBase, float* __restrict__ gBase)
{
  int z = blockIdx.z;
  void* C = (z == 0) ? C0 : (z == 1) ? C1 : (z == 2) ? C2 : C3;
  const float* bias = (z == 0) ? b0 : (z == 1) ? b1 : (z == 2) ? b2 : b3;
  int obf = (obf16mask >> z) & 1;
  int ilv = (ileaveG && z < 2) ? ileaveG : 0;
  int wave = threadIdx.x >> 6, lane = threadIdx.x & 63;
  int mt = blockIdx.x * 4 + wave;
  int tg0 = blockIdx.y * 2;
  f32x4 acc[2];
  acc[0] = (f32x4){0.f, 0.f, 0.f, 0.f};
  acc[1] = (f32x4){0.f, 0.f, 0.f, 0.f};
  const bf16x8* ah = (const bf16x8*)Ah + (size_t)mt * KC * 64 + lane;
  const bf16x8* al = (const bf16x8*)Al + (size_t)mt * KC * 64 + lane;
  const bf16x8* bh = (const bf16x8*)Bh + (size_t)z * bStride8 + lane;
  const bf16x8* bl = (const bf16x8*)Bl + (size_t)z * bStride8 + lane;
  for (int c = 0; c < KC; ++c) {
    bf16x8 a_h = ah[c * 64];
    bf16x8 a_l = al[c * 64];
#pragma unroll
    for (int t = 0; t < 2; ++t) {
      size_t bo = (size_t)((tg0 + t) * KC + c) * 64;
      bf16x8 b_h = bh[bo];
      bf16x8 b_l = bl[bo];
      acc[t] = __builtin_amdgcn_mfma_f32_16x16x32_bf16(a_h, b_h, acc[t], 0, 0, 0);
      acc[t] = __builtin_amdgcn_mfma_f32_16x16x32_bf16(a_h, b_l, acc[t], 0, 0, 0);
      acc[t] = __builtin_amdgcn_mfma_f32_16x16x32_bf16(a_l, b_h, acc[t], 0, 0, 0);
    }
  }
  int quad = lane >> 4, cn = lane & 15;
#pragma unroll
  for (int t = 0; t < 2; ++t) {
    int col = (tg0 + t) * 16 + cn;
    float bv = bias ? bias[col] : 0.0f;
#pragma unroll
    for (int r = 0; r < 4; ++r) {
      int row = mt * 16 + quad * 4 + r;
      float v = acc[t][r] + bv;
      acc[t][r] = v;
      if (ilv) {
        size_t addr = (size_t)row * (2 * N) + (size_t)(col / ilv) * (2 * ilv)
                    + z * ilv + (col % ilv);
        ((unsigned short*)C0)[addr] = f2bf(v);
      } else if (obf) {
        ((unsigned short*)C)[(size_t)row * N + col] = f2bf(v);
      } else {
        ((float*)C)[(size_t)row * N + col] = v;
      }
    }
  }
  if ((fgmask >> z) & 1) {
    const float* af = aBase + (size_t)z * 2 * N;
    const float* ag = af + N;
    float af0 = af[tg0 * 16 + cn], af1 = af[(tg0 + 1) * 16 + cn];
    float ag0 = ag[tg0 * 16 + cn], ag1 = ag[(tg0 + 1) * 16 + cn];
#pragma unroll
    for (int r = 0; r < 4; ++r) {
      float pf = acc[0][r] * af0 + acc[1][r] * af1;
      float pg = acc[0][r] * ag0 + acc[1][r] * ag1;
#pragma unroll
      for (int off = 1; off < 16; off <<= 1) {
        pf += __shfl_xor(pf, off);
        pg += __shfl_xor(pg, off);
      }
      if (cn == 0) {
        int row = mt * 16 + quad * 4 + r;
        size_t fo = fgIleave ? ((size_t)row * 2 + z) : ((size_t)z * NN + row);
        atomicAdd(fBase + fo, pf);
        atomicAdd(gBase + fo, pg);
      }
    }
  }
}

// ---------------- conv GAT: wave-per-row, BOTH heads, LDS att, in-reg combine
// fI/gI interleaved [NN][2]; hh interleaved [row][grp][head][G].
// MODE 1 (D=256,G=4): apack(selu(0.5*(o0+o1) + res)); MODE 2 (D=128,G=2): emb.
template<int D, int MODE>
__global__ __launch_bounds__(256) void gat_wave(const unsigned short* __restrict__ nbr,
    const int* __restrict__ deg, const int* __restrict__ selfflag,
    const float* __restrict__ fI, const float* __restrict__ gI,
    const unsigned short* __restrict__ hh, const float* __restrict__ bias,
    const float* __restrict__ res,
    unsigned short* __restrict__ Ah, unsigned short* __restrict__ Al,
    float* __restrict__ emb)
{
  __shared__ float2 attS[4][128];
  __shared__ unsigned short jS[4][128];
  int t = threadIdx.x, lane = t & 63, w = t >> 6;
  int row = blockIdx.x * 4 + w;
  int dg = deg[row];
  int klen = dg + (selfflag[row] ? 0 : 1);   // gat_adj = adj + I
  if (klen > 128) klen = 128;
  float f0 = fI[2 * row], f1 = fI[2 * row + 1];
  float e00 = -3.0e38f, e01 = -3.0e38f, e10 = -3.0e38f, e11 = -3.0e38f;
  int j0 = 0, j1 = 0;
  if (lane < klen) {
    j0 = (lane < dg) ? (int)nbr[(size_t)row * CAP + lane] : row;
    float2 gj = *(const float2*)(gI + 2 * j0);
    e00 = leaky2(f0 + gj.x);
    e01 = leaky2(f1 + gj.y);
  }
  if (lane + 64 < klen) {
    j1 = (lane + 64 < dg) ? (int)nbr[(size_t)row * CAP + lane + 64] : row;
    float2 gj = *(const float2*)(gI + 2 * j1);
    e10 = leaky2(f0 + gj.x);
    e11 = leaky2(f1 + gj.y);
  }
  float m0 = wave_max(fmaxf(e00, e10));
  float m1 = wave_max(fmaxf(e01, e11));
  float x00 = (lane < klen) ? __expf(e00 - m0) : 0.0f;
  float x10 = (lane + 64 < klen) ? __expf(e10 - m0) : 0.0f;
  float x01 = (lane < klen) ? __expf(e01 - m1) : 0.0f;
  float x11 = (lane + 64 < klen) ? __expf(e11 - m1) : 0.0f;
  float inv0 = 1.0f / wave_sum(x00 + x10);
  float inv1 = 1.0f / wave_sum(x01 + x11);
  if (lane < klen)      { attS[w][lane] = (float2){x00 * inv0, x01 * inv1};
                          jS[w][lane] = (unsigned short)j0; }
  if (lane + 64 < klen) { attS[w][lane + 64] = (float2){x10 * inv0, x11 * inv1};
                          jS[w][lane + 64] = (unsigned short)j1; }

  if (MODE == 1) {
    const unsigned short* hp = hh + 8 * lane;
    float4 a0 = {0.f, 0.f, 0.f, 0.f}, a1 = {0.f, 0.f, 0.f, 0.f};
    for (int k = 0; k < klen; ++k) {
      float2 a = attS[w][k];
      u16x8 hv = *(const u16x8*)(hp + (size_t)jS[w][k] * 512);
      a0.x += a.x * bf2f(hv[0]); a1.x += a.y * bf2f(hv[4]);
      a0.y += a.x * bf2f(hv[1]); a1.y += a.y * bf2f(hv[5]);
      a0.z += a.x * bf2f(hv[2]); a1.z += a.y * bf2f(hv[6]);
      a0.w += a.x * bf2f(hv[3]); a1.w += a.y * bf2f(hv[7]);
    }
    a0.x = leaky2(a0.x); a0.y = leaky2(a0.y); a0.z = leaky2(a0.z); a0.w = leaky2(a0.w);
    a1.x = leaky2(a1.x); a1.y = leaky2(a1.y); a1.z = leaky2(a1.z); a1.w = leaky2(a1.w);
    float q0 = wave_sum(a0.x * a0.x + a0.y * a0.y + a0.z * a0.z + a0.w * a0.w);
    float q1 = wave_sum(a1.x * a1.x + a1.y * a1.y + a1.z * a1.z + a1.w * a1.w);
    float n0 = 1.0f / fmaxf(sqrtf(q0), 1e-12f);
    float n1 = 1.0f / fmaxf(sqrtf(q1), 1e-12f);
    int c = 4 * lane;
    float4 b0v = *(const float4*)(bias + c);
    float4 b1v = *(const float4*)(bias + D + c);
    float4 hv = *(const float4*)(res + (size_t)row * D + c);
    float o0 = selu_f(0.5f * ((a0.x * n0 + b0v.x) + (a1.x * n1 + b1v.x)) + hv.x);
    float o1 = selu_f(0.5f * ((a0.y * n0 + b0v.y) + (a1.y * n1 + b1v.y)) + hv.y);
    float o2 = selu_f(0.5f * ((a0.z * n0 + b0v.z) + (a1.z * n1 + b1v.z)) + hv.z);
    float o3 = selu_f(0.5f * ((a0.w * n0 + b0v.w) + (a1.w * n1 + b1v.w)) + hv.w);
    write_apack4(Ah, Al, 8, row, c, o0, o1, o2, o3);
  } else {
    const unsigned short* hp = hh + 4 * lane;
    float a0x = 0.f, a0y = 0.f, a1x = 0.f, a1y = 0.f;
    for (int k = 0; k < klen; ++k) {
      float2 a = attS[w][k];
      ushort4 hv = *(const ushort4*)(hp + (size_t)jS[w][k] * 256);
      a0x += a.x * bf2f(hv.x); a0y += a.x * bf2f(hv.y);
      a1x += a.y * bf2f(hv.z); a1y += a.y * bf2f(hv.w);
    }
    a0x = leaky2(a0x); a0y = leaky2(a0y);
    a1x = leaky2(a1x); a1y = leaky2(a1y);
    float q0 = wave_sum(a0x * a0x + a0y * a0y);
    float q1 = wave_sum(a1x * a1x + a1y * a1y);
    float n0 = 1.0f / fmaxf(sqrtf(q0), 1e-12f);
    float n1 = 1.0f / fmaxf(sqrtf(q1), 1e-12f);
    int c = 2 * lane;
    float2 b0v = *(const float2*)(bias + c);
    float2 b1v = *(const float2*)(bias + D + c);
    float2 r0 = *(const float2*)(res + (size_t)row * D + c);
    float2 r1 = *(const float2*)(res + (size_t)NN * D + (size_t)row * D + c);
    float2 o;
    o.x = 0.5f * (((a0x * n0 + b0v.x) + r0.x) + ((a1x * n1 + b1v.x) + r1.x));
    o.y = 0.5f * (((a0y * n0 + b0v.y) + r0.y) + ((a1y * n1 + b1v.y) + r1.y));
    *(float2*)(emb + (size_t)row * D + c) = o;
  }
}

// ---------------- fused hybrid: wave-per-row; LDS att; one 16B load/branch ---
__global__ __launch_bounds__(256) void fused_hybrid(const unsigned short* __restrict__ nbr,
    const int* __restrict__ deg, const float* __restrict__ dis,
    const unsigned short* __restrict__ XH,   // interleaved [row][grp][branch][4]
    const float* __restrict__ f, const float* __restrict__ g,
    const float* __restrict__ bias, const float* __restrict__ eta,
    float* __restrict__ hout, unsigned short* __restrict__ Ah,
    unsigned short* __restrict__ Al)
{
  __shared__ float attS[4][128];
  __shared__ float djS[4][128];
  __shared__ unsigned short jS[4][128];
  int t = threadIdx.x, lane = t & 63, w = t >> 6;
  int row = blockIdx.x * 4 + w;
  int klen = deg[row];
  if (klen > 128) klen = 128;
  float fi = f[row];
  float e0 = -3.0e38f, e1 = -3.0e38f;
  int j0 = 0, j1 = 0;
  float d0 = 0.f, d1 = 0.f;
  if (lane < klen) {
    j0 = (int)nbr[(size_t)row * CAP + lane];
    d0 = dis[j0];
    float ev = leaky2(fi + g[j0]);
    e0 = (d0 > 0.0f) ? ev : -3.0e38f;
  }
  if (lane + 64 < klen) {
    j1 = (int)nbr[(size_t)row * CAP + lane + 64];
    d1 = dis[j1];
    float ev = leaky2(fi + g[j1]);
    e1 = (d1 > 0.0f) ? ev : -3.0e38f;
  }
  float m = wave_max(fmaxf(e0, e1));
  float x0 = (lane < klen) ? __expf(e0 - m) : 0.0f;
  float x1 = (lane + 64 < klen) ? __expf(e1 - m) : 0.0f;
  float inv = 1.0f / wave_sum(x0 + x1);
  if (lane < klen)      { attS[w][lane] = x0 * inv;      djS[w][lane] = d0;
                          jS[w][lane] = (unsigned short)j0; }
  if (lane + 64 < klen) { attS[w][lane + 64] = x1 * inv; djS[w][lane + 64] = d1;
                          jS[w][lane + 64] = (unsigned short)j1; }

  const unsigned short* hp = XH + 8 * lane;   // branch0=xw [0..3], branch1=hh [4..7]
  float4 accG = {0.f, 0.f, 0.f, 0.f};
  float4 accA = {0.f, 0.f, 0.f, 0.f};
  for (int k = 0; k < klen; ++k) {
    float a = attS[w][k];
    float dj = djS[w][k];
    u16x8 hv = *(const u16x8*)(hp + (size_t)jS[w][k] * 512);
    accG.x += dj * bf2f(hv[0]); accA.x += a * bf2f(hv[4]);
    accG.y += dj * bf2f(hv[1]); accA.y += a * bf2f(hv[5]);
    accG.z += dj * bf2f(hv[2]); accA.z += a * bf2f(hv[6]);
    accG.w += dj * bf2f(hv[3]); accA.w += a * bf2f(hv[7]);
  }
  accA.x = leaky2(accA.x); accA.y = leaky2(accA.y);
  accA.z = leaky2(accA.z); accA.w = leaky2(accA.w);
  float q = wave_sum(accA.x * accA.x + accA.y * accA.y +
                     accA.z * accA.z + accA.w * accA.w);
  float nsc = 1.0f / fmaxf(sqrtf(q), 1e-12f);
  float di = dis[row];
  float et = eta[0];
  const float* bp = bias + 4 * lane;
  float ga[4] = {accG.x, accG.y, accG.z, accG.w};
  float at[4] = {accA.x, accA.y, accA.z, accA.w};
  float hv4[4];
#pragma unroll
  for (int u = 0; u < 4; ++u) {
    float gcn = leaky2(di * ga[u]);
    float gat = at[u] * nsc + bp[u];
    float z = et * gcn + (1.0f - et) * gat;
    hv4[u] = selu_f(z);
  }
  *(float4*)(hout + (size_t)row * 256 + 4 * lane) =
      (float4){hv4[0], hv4[1], hv4[2], hv4[3]};
  write_apack4(Ah, Al, 8, row, 4 * lane, hv4[0], hv4[1], hv4[2], hv4[3]);
}

// ---------------- fused decoder MLPs (leaky 0.01), 16 rows/block -------------
__global__ __launch_bounds__(256) void decoder_fused(const float* __restrict__ emb,
    const float* __restrict__ tf1_W, const float* __restrict__ tf1_b,
    const float* __restrict__ tf2_W, const float* __restrict__ tf2_b,
    const float* __restrict__ tg1_W, const float* __restrict__ tg1_b,
    const float* __restrict__ tg2_W, const float* __restrict__ tg2_b,
    float* __restrict__ TF, float* __restrict__ TG)
{
  __shared__ float embS[128 * 16];   // [k][r]
  __shared__ float t1S[128 * 16];    // [c][r]
  int t = threadIdx.x;
  int r0 = blockIdx.x * 16;
  for (int e = t; e < 2048; e += 256) {
    int r = e >> 7, k = e & 127;
    embS[k * 16 + r] = emb[(size_t)(r0 + r) * 128 + k];
  }
  __syncthreads();
  int c = t & 127, half = t >> 7;
  const float* W1 = (c < 64) ? tf1_W : tg1_W;
  int c1 = c & 63;
  float b1v = (c < 64) ? tf1_b[c1] : tg1_b[c1];
  float acc1[8];
#pragma unroll
  for (int r = 0; r < 8; ++r) acc1[r] = b1v;
  for (int k = 0; k < 128; ++k) {
    float wv = W1[k * 64 + c1];
#pragma unroll
    for (int r = 0; r < 8; ++r) acc1[r] += wv * embS[k * 16 + half * 8 + r];
  }
#pragma unroll
  for (int r = 0; r < 8; ++r) {
    float v = acc1[r];
    t1S[c * 16 + half * 8 + r] = v > 0.0f ? v : 0.01f * v;
  }
  __syncthreads();
  int c2 = t & 63, rg = t >> 6;
  const float* W2 = (c2 < 32) ? tf2_W : tg2_W;
  int cc = c2 & 31;
  float b2v = (c2 < 32) ? tf2_b[cc] : tg2_b[cc];
  int koff = (c2 < 32) ? 0 : 64;
  float acc2[4];
#pragma unroll
  for (int r = 0; r < 4; ++r) acc2[r] = b2v;
  for (int k = 0; k < 64; ++k) {
    float wv = W2[k * 32 + cc];
#pragma unroll
    for (int r = 0; r < 4; ++r) acc2[r] += wv * t1S[(koff + k) * 16 + rg * 4 + r];
  }
  float* O = (c2 < 32) ? TF : TG;
#pragma unroll
  for (int r = 0; r < 4; ++r) {
    float v = acc2[r];
    v = v > 0.0f ? v : 0.01f * v;
    O[(size_t)(r0 + rg * 4 + r) * 32 + cc] = v;
  }
}

// ---------------- final gather + MLP -----------------------------------------
__global__ void decode_mlp(const float* __restrict__ tf,
    const float* __restrict__ tg, const int* __restrict__ samp,
    const float* __restrict__ W, const float* __restrict__ b,
    float* __restrict__ out, int B)
{
  int bid = blockIdx.x * blockDim.x + threadIdx.x;
  if (bid >= B) return;
  int s0 = samp[2 * bid], s1 = samp[2 * bid + 1];
  float a0 = b[0], a1 = b[1];
#pragma unroll
  for (int c = 0; c < 32; ++c) {
    float v = tf[(size_t)s0 * 32 + c];
    a0 += v * W[2 * c];
    a1 += v * W[2 * c + 1];
  }
#pragma unroll
  for (int c = 0; c < 32; ++c) {
    float v = tg[(size_t)s1 * 32 + c];
    a0 += v * W[2 * (32 + c)];
    a1 += v * W[2 * (32 + c) + 1];
  }
  out[2 * bid] = a0;
  out[2 * bid + 1] = a1;
}

// ---------------- driver ------------------------------------------------------
extern "C" void kernel_launch(void* const* d_in, const int* in_sizes, int n_in,
                              void* d_out, int out_size, void* d_ws, size_t ws_size,
                              hipStream_t stream)
{
  const float* x      = (const float*)d_in[0];
  const float* adj    = (const float*)d_in[1];
  const float* gcn_W  = (const float*)d_in[2];
  const float* gcn_b  = (const float*)d_in[3];
  const float* hgat_W = (const float*)d_in[4];
  const float* hgat_a = (const float*)d_in[5];
  const float* hgat_b = (const float*)d_in[6];
  const float* eta    = (const float*)d_in[7];
  const float* l1_W   = (const float*)d_in[8];
  const float* l1_a   = (const float*)d_in[9];
  const float* l1_b   = (const float*)d_in[10];
  const float* l2_W   = (const float*)d_in[11];
  const float* l2_a   = (const float*)d_in[12];
  const float* l2_b   = (const float*)d_in[13];
  const float* l2_rW  = (const float*)d_in[14];
  const float* l2_rb  = (const float*)d_in[15];
  const float* tf1_W  = (const float*)d_in[16];
  const float* tf1_b  = (const float*)d_in[17];
  const float* tf2_W  = (const float*)d_in[18];
  const float* tf2_b  = (const float*)d_in[19];
  const float* tg1_W  = (const float*)d_in[20];
  const float* tg1_b  = (const float*)d_in[21];
  const float* tg2_W  = (const float*)d_in[22];
  const float* tg2_b  = (const float*)d_in[23];
  const float* mlp_W  = (const float*)d_in[24];
  const float* mlp_b  = (const float*)d_in[25];
  const int*   samp   = (const int*)d_in[26];
  float* out = (float*)d_out;

  char* ws = (char*)d_ws;
  size_t off = 0;
  auto alloc = [&](size_t bytes) -> void* {
    void* p = ws + off;
    off += (bytes + 255) & ~(size_t)255;
    return p;
  };
  unsigned short* nbr = (unsigned short*)alloc((size_t)NN * CAP * 2);
  int*   deg = (int*)  alloc((size_t)NN * 4);
  int*   sfl = (int*)  alloc((size_t)NN * 4);
  float* dis = (float*)alloc((size_t)NN * 4);
  float* fgZ = (float*)alloc((size_t)10 * NN * 4);
  unsigned short* H0b = (unsigned short*)alloc((size_t)2 * NN * 256 * 2);  // xw|hh interleaved
  float* Hh  = (float*)alloc((size_t)NN * 256 * 4);                        // h (fp32 residual)
  unsigned short* HHb = (unsigned short*)alloc((size_t)2 * NN * 256 * 2);  // conv1 heads interleaved
  unsigned short* Qb  = (unsigned short*)alloc((size_t)2 * NN * 128 * 2);  // conv2 heads interleaved
  float* Qr  = (float*)alloc((size_t)2 * NN * 128 * 4);                    // conv2 residual fp32
  float* emb = (float*)alloc((size_t)NN * 128 * 4);
  float* TF  = (float*)alloc((size_t)NN * 32 * 4);
  float* TG  = (float*)alloc((size_t)NN * 32 * 4);
  unsigned short* APH = (unsigned short*)alloc((size_t)NN * 512 * 2);  // shared A arena
  unsigned short* APL = (unsigned short*)alloc((size_t)NN * 512 * 2);
  unsigned short* BPH = (unsigned short*)alloc((size_t)65536 * 8 * 2);
  unsigned short* BPL = (unsigned short*)alloc((size_t)65536 * 8 * 2);
  (void)ws_size; (void)n_in; (void)in_sizes; (void)out_size;

  float* fv0 = fgZ;                 // [NN] flat   (hybrid, z=1 of gemm1)
  float* gv0 = fgZ + NN;
  float* fI1 = fgZ + 2 * NN;        // [NN][2] interleaved (conv1 heads)
  float* gI1 = fgZ + 4 * NN;
  float* fI2 = fgZ + 6 * NN;        // [NN][2] interleaved (conv2 heads)
  float* gI2 = fgZ + 8 * NN;

  const float* nil = nullptr;

  // 1. prep: sparsify adjacency + pack all weights + x + zero fg (one dispatch)
  prep_kernel<<<NN + 2032, 256, 0, stream>>>(adj, nbr, deg, sfl, dis,
      gcn_W, hgat_W, l1_W, l2_W, l2_rW, x, BPH, BPL, APH, APL, fgZ);

  // 2-3. hybrid layer (xw/hh interleaved; fg flat on z=1)
  gemm_mfma<<<dim3(96, 8, 2), 256, 0, stream>>>(APH, APL, BPH, BPL,
      H0b, nullptr, nullptr, nullptr, gcn_b, nil, nil, nil,
      16, 256, 16384, 0x0, 4,
      0x2, 0, hgat_a - 512, fv0 - NN, gv0 - NN);
  fused_hybrid<<<NN / 4, 256, 0, stream>>>(nbr, deg, dis, H0b,
      fv0, gv0, hgat_b, eta, Hh, APH, APL);

  // 4-5. ConvLayer1 (heads interleaved; fg interleaved; in-register combine)
  gemm_mfma<<<dim3(96, 8, 2), 256, 0, stream>>>(APH, APL, BPH + (size_t)32768 * 8,
      BPL + (size_t)32768 * 8, HHb, nullptr, nullptr, nullptr,
      nil, nil, nil, nil, 8, 256, 8192, 0x0, 4,
      0x3, 1, l1_a, fI1, gI1);
  gat_wave<256, 1><<<NN / 4, 256, 0, stream>>>(nbr, deg, sfl, fI1, gI1, HHb, l1_b,
      Hh, APH, APL, nullptr);

  // 6-7. ConvLayer2 (heads interleaved z<2; residuals fp32 z>=2; fg interleaved)
  gemm_mfma<<<dim3(96, 4, 4), 256, 0, stream>>>(APH, APL, BPH + (size_t)49152 * 8,
      BPL + (size_t)49152 * 8,
      Qb, nullptr, Qr, Qr + (size_t)NN * 128,
      nil, nil, l2_rb, l2_rb + 128, 8, 128, 4096, 0x0, 2,
      0x3, 1, l2_a, fI2, gI2);
  gat_wave<128, 2><<<NN / 4, 256, 0, stream>>>(nbr, deg, sfl, fI2, gI2, Qb, l2_b,
      Qr, nullptr, nullptr, emb);

  // 8. fused decoder MLPs
  decoder_fused<<<NN / 16, 256, 0, stream>>>(emb, tf1_W, tf1_b, tf2_W, tf2_b,
      tg1_W, tg1_b, tg2_W, tg2_b, TF, TG);

  // 9. pair gather + final MLP
  decode_mlp<<<16, 256, 0, stream>>>(TF, TG, samp, mlp_W, mlp_b, out, 4096);
}